// Round 10
// baseline (576.376 us; speedup 1.0000x reference)
//
#include <hip/hip_runtime.h>

// Problem constants
#define BATCH 4096
#define FEATS 26
#define BAG   8
#define EDIM  64
#define INDIM 1664   // 26*64

typedef short bf16x8 __attribute__((ext_vector_type(8)));
typedef float f32x4  __attribute__((ext_vector_type(4)));
typedef unsigned short u16x8 __attribute__((ext_vector_type(8)));

__device__ __forceinline__ unsigned short f2bf(float f) {
    unsigned u = __float_as_uint(f);
    unsigned r = (u + 0x7FFFu + ((u >> 16) & 1u)) >> 16;
    return (unsigned short)r;
}
__device__ __forceinline__ float bf2f(unsigned short h) {
    return __uint_as_float((unsigned)h << 16);
}
// async global->LDS, 16B per lane. HW dst = wave-uniform base + lane*16.
__device__ __forceinline__ void async_cp16(const void* g, void* lds_base_uniform) {
    __builtin_amdgcn_global_load_lds(
        (const __attribute__((address_space(1))) unsigned int*)g,
        (__attribute__((address_space(3))) unsigned int*)lds_base_uniform,
        16, 0, 0);
}
// s_waitcnt with only vmcnt constrained (lgkm=15, exp=7 i.e. no wait)
#define WAITCNT_VM(n) __builtin_amdgcn_s_waitcnt(0x0F70 | (n))

// ---------------- batched weight transpose + fp32->bf16 (1 launch, 6 weights) ----
__global__ __launch_bounds__(256) void transpose_all(
    const float* __restrict__ w10, unsigned short* __restrict__ o10,
    const float* __restrict__ w20, unsigned short* __restrict__ o20,
    const float* __restrict__ w11, unsigned short* __restrict__ o11,
    const float* __restrict__ w21, unsigned short* __restrict__ o21,
    const float* __restrict__ w12, unsigned short* __restrict__ o12,
    const float* __restrict__ w22, unsigned short* __restrict__ o22)
{
    const float* in; unsigned short* out; int R, C;
    switch (blockIdx.z) {
        case 0:  in = w10; out = o10; R = INDIM; C = 1024;  break;
        case 1:  in = w20; out = o20; R = 1024;  C = INDIM; break;
        case 2:  in = w11; out = o11; R = INDIM; C = 1024;  break;
        case 3:  in = w21; out = o21; R = 1024;  C = INDIM; break;
        case 4:  in = w12; out = o12; R = INDIM; C = 512;   break;
        default: in = w22; out = o22; R = 512;   C = INDIM; break;
    }
    const int c0 = blockIdx.x * 64, r0 = blockIdx.y * 64;
    if (c0 >= C || r0 >= R) return;

    __shared__ unsigned short tile[64][65];
    const int t = threadIdx.x;
    const int tc = t & 63, tr = t >> 6;
#pragma unroll
    for (int i = 0; i < 16; ++i) {
        int r = tr + i * 4;
        tile[r][tc] = f2bf(in[(long long)(r0 + r) * C + c0 + tc]);
    }
    __syncthreads();
    const int wr = t >> 3, wc = t & 7;
#pragma unroll
    for (int half = 0; half < 2; ++half) {
        int row = wr + half * 32;
        u16x8 v;
#pragma unroll
        for (int j = 0; j < 8; ++j) v[j] = tile[wc * 8 + j][row];
        *(u16x8*)(out + (long long)(c0 + row) * R + r0 + wc * 8) = v;
    }
}

// ---------------- embedding bag (round-0 form) ----------------
__global__ __launch_bounds__(256) void embed_pool(
    const int* __restrict__ x, const float* __restrict__ emb,
    unsigned short* __restrict__ feat)
{
    int bag  = blockIdx.x * 4 + (threadIdx.x >> 6);
    int lane = threadIdx.x & 63;
    int b = bag / FEATS;
    int f = bag - b * FEATS;
    const int* xs = x + (long long)bag * BAG;
    float s = 0.f;
#pragma unroll
    for (int l = 0; l < BAG; ++l) {
        int id = xs[l];
        s += emb[(long long)id * EDIM + lane];
    }
    feat[(long long)b * INDIM + f * EDIM + lane] = f2bf(s);
}

// ------------- bf16 MFMA GEMM: 64x128 tile, co-resident + row-grouped swizzle ----
// 256 threads = 4 waves, wave tile 32x64 (wm=wave&1 row half, wn=wave>>1 col
// half), BK=32, NBUF=4, counted vmcnt (3 cp16/tile/wave; wait 6 in main loop).
// LDS 48KB + launch_bounds(256,3) -> 2-3 blocks/CU CO-RESIDENT (grids 512/832/
// 256/832 > 256 CUs): cross-block waves hide the per-K-iter barrier drain
// (m114 mechanism) -- the one thing R7/R9's 1-block/CU structure lacked.
// Row-grouped XCD swizzle (R7, proven -68us): col-fastest linear, chunk
// q=nwg/8 per XCD -> each XCD owns 8 contiguous 64-row A-panels x all cols;
// working set A 0.5-1.7MB + B 1.7-3.4MB ~= L2-resident, so the 1.5x staging
// bytes of the smaller tile are L2-served (R1's M-fastest chunking instead
// streamed all 13.6MB of A per XCD -- the orientation, not the tile size,
// was its flaw).
// LDS XOR swizzle: slot (row, s) holds global k-chunk s ^ ((row>>1)&3) (16B).
#define NBUF 4
__global__ __launch_bounds__(256, 3) void gemm_bf16(
    const unsigned short* __restrict__ A, const unsigned short* __restrict__ Wt,
    const float* __restrict__ bias, const unsigned short* __restrict__ res,
    unsigned short* __restrict__ out, int M, int N, int K, int do_relu)
{
    __shared__ unsigned short As[NBUF * 64 * 32];    // 16 KB
    __shared__ unsigned short Bs[NBUF * 128 * 32];   // 32 KB

    const int t = threadIdx.x;
    // ---- row-grouped XCD swizzle (nwg % 8 == 0 for all grids here) ----
    const int nxg = gridDim.x;
    const int lin = blockIdx.y * nxg + blockIdx.x;
    const int q   = (nxg * gridDim.y) >> 3;
    const int tile = (lin & 7) * q + (lin >> 3);
    const int ty  = tile / nxg;
    const int bCol = (tile - ty * nxg) * 128;
    const int bRow = ty * 64;

    const int wave = t >> 6, lane = t & 63;
    const int wm = wave & 1, wn = wave >> 1;       // wn in 0..1
    const int lm = lane & 15, quad = lane >> 4;

    const int srow = lane >> 2;
    const int sq   = (lane & 3) ^ ((lane >> 3) & 3);
    const int slot = (quad ^ ((lm >> 1) & 3)) * 8;

    // staging: wave stages A rows [w*16,w*16+16) (1 cp16) and B rows
    // [w*16,w*16+16) + [64+w*16,...) (2 cp16)
    const unsigned short* Ag  = A  + (long long)(bRow + wave * 16 + srow) * K + sq * 8;
    const unsigned short* Bg0 = Wt + (long long)(bCol + wave * 16 + srow) * K + sq * 8;
    const unsigned short* Bg1 = Bg0 + 64 * (long long)K;
    unsigned short* AsW  = As + wave * 512;          // + buf*2048
    unsigned short* BsW0 = Bs + wave * 512;          // + buf*4096
    unsigned short* BsW1 = Bs + 2048 + wave * 512;   // + buf*4096

    const int T = K / 32;
    f32x4 acc[2][4] = {};

#define ISSUE(t_)  do { int _b = (t_) & (NBUF - 1);                               \
        async_cp16(Ag  + (long long)(t_) * 32, AsW  + _b * 2048);                 \
        async_cp16(Bg0 + (long long)(t_) * 32, BsW0 + _b * 4096);                 \
        async_cp16(Bg1 + (long long)(t_) * 32, BsW1 + _b * 4096); } while (0)

#define COMPUTE(t_) do { int _b = (t_) & (NBUF - 1);                              \
        const unsigned short* _a  = As + _b * 2048;                               \
        const unsigned short* _bp = Bs + _b * 4096;                               \
        bf16x8 af[2], bf[4];                                                      \
        _Pragma("unroll")                                                         \
        for (int i = 0; i < 2; ++i)                                               \
            af[i] = *(const bf16x8*)&_a[(wm * 32 + i * 16 + lm) * 32 + slot];     \
        _Pragma("unroll")                                                         \
        for (int j = 0; j < 4; ++j)                                               \
            bf[j] = *(const bf16x8*)&_bp[(wn * 64 + j * 16 + lm) * 32 + slot];    \
        _Pragma("unroll")                                                         \
        for (int i = 0; i < 2; ++i)                                               \
            _Pragma("unroll")                                                     \
            for (int j = 0; j < 4; ++j)                                           \
                acc[i][j] = __builtin_amdgcn_mfma_f32_16x16x32_bf16(              \
                    af[i], bf[j], acc[i][j], 0, 0, 0); } while (0)

    ISSUE(0);
    ISSUE(1);
    for (int tt = 0; tt < T - 2; ++tt) {
        ISSUE(tt + 2);                 // lands in buf[(tt+2)&3] = buf[(tt-2)&3]: reads done
        WAITCNT_VM(6);                 // tile tt's 3 loads complete (tt+1,tt+2 in flight)
        asm volatile("" ::: "memory");
        __builtin_amdgcn_s_barrier();
        asm volatile("" ::: "memory");
        COMPUTE(tt);
    }
    WAITCNT_VM(3);
    asm volatile("" ::: "memory");
    __builtin_amdgcn_s_barrier();
    asm volatile("" ::: "memory");
    COMPUTE(T - 2);
    WAITCNT_VM(0);
    asm volatile("" ::: "memory");
    __builtin_amdgcn_s_barrier();
    asm volatile("" ::: "memory");
    COMPUTE(T - 1);

    // ---- epilogue: bias (+res) (+relu), bf16 out ----
#pragma unroll
    for (int i = 0; i < 2; ++i) {
#pragma unroll
        for (int j = 0; j < 4; ++j) {
            int col = bCol + wn * 64 + j * 16 + lm;
            float bv = bias[col];
#pragma unroll
            for (int r = 0; r < 4; ++r) {
                int row = bRow + wm * 32 + i * 16 + quad * 4 + r;
                float v = acc[i][j][r] + bv;
                if (res) v += bf2f(res[(long long)row * N + col]);
                if (do_relu) v = fmaxf(v, 0.f);
                out[(long long)row * N + col] = f2bf(v);
            }
        }
    }
#undef ISSUE
#undef COMPUTE
}

// ---------------- final linear + sigmoid ----------------
__global__ __launch_bounds__(256) void final_head(
    const unsigned short* __restrict__ feat, const float* __restrict__ lin_w,
    const float* __restrict__ lin_b, float* __restrict__ out)
{
    int row  = blockIdx.x * 4 + (threadIdx.x >> 6);
    int lane = threadIdx.x & 63;
    const unsigned short* fr = feat + (long long)row * INDIM;
    float s = 0.f;
#pragma unroll
    for (int it = 0; it < INDIM / 64; ++it)
        s += bf2f(fr[it * 64 + lane]) * lin_w[it * 64 + lane];
#pragma unroll
    for (int off = 32; off; off >>= 1)
        s += __shfl_down(s, off, 64);
    if (lane == 0)
        out[row] = 1.f / (1.f + __expf(-(s + lin_b[0])));
}

extern "C" void kernel_launch(void* const* d_in, const int* in_sizes, int n_in,
                              void* d_out, int out_size, void* d_ws, size_t ws_size,
                              hipStream_t stream) {
    const int*   x    = (const int*)  d_in[0];
    const float* emb  = (const float*)d_in[1];
    const float* w1_0 = (const float*)d_in[2];
    const float* b1_0 = (const float*)d_in[3];
    const float* w2_0 = (const float*)d_in[4];
    const float* b2_0 = (const float*)d_in[5];
    const float* w1_1 = (const float*)d_in[6];
    const float* b1_1 = (const float*)d_in[7];
    const float* w2_1 = (const float*)d_in[8];
    const float* b2_1 = (const float*)d_in[9];
    const float* w1_2 = (const float*)d_in[10];
    const float* b1_2 = (const float*)d_in[11];
    const float* w2_2 = (const float*)d_in[12];
    const float* b2_2 = (const float*)d_in[13];
    const float* linw = (const float*)d_in[14];
    const float* linb = (const float*)d_in[15];
    float* out = (float*)d_out;

    // ws layout (bf16 elements)
    unsigned short* feat = (unsigned short*)d_ws;            // [4096,1664]
    unsigned short* h    = feat + (long long)BATCH * INDIM;  // [4096,1024]
    unsigned short* p    = h + (long long)BATCH * 1024;
    unsigned short* w1_0t = p; p += 1024 * INDIM;
    unsigned short* w2_0t = p; p += INDIM * 1024;
    unsigned short* w1_1t = p; p += 1024 * INDIM;
    unsigned short* w2_1t = p; p += INDIM * 1024;
    unsigned short* w1_2t = p; p += 512 * INDIM;
    unsigned short* w2_2t = p; p += INDIM * 512;

    // 0) all weight transposes in ONE launch (z = weight index)
    transpose_all<<<dim3(26, 26, 6), 256, 0, stream>>>(
        w1_0, w1_0t, w2_0, w2_0t, w1_1, w1_1t, w2_1, w2_1t, w1_2, w1_2t, w2_2, w2_2t);

    // 1) embedding bag -> bf16 feat
    embed_pool<<<BATCH * FEATS / 4, 256, 0, stream>>>(x, emb, feat);

    // 2) residual blocks (64x128 tile, 2-3 blocks/CU, row-grouped XCD swizzle)
    gemm_bf16<<<dim3(1024/128, BATCH/64), 256, 0, stream>>>(
        feat, w1_0t, b1_0, nullptr, h, BATCH, 1024, INDIM, 1);
    gemm_bf16<<<dim3(INDIM/128, BATCH/64), 256, 0, stream>>>(
        h, w2_0t, b2_0, feat, feat, BATCH, INDIM, 1024, 1);
    gemm_bf16<<<dim3(1024/128, BATCH/64), 256, 0, stream>>>(
        feat, w1_1t, b1_1, nullptr, h, BATCH, 1024, INDIM, 1);
    gemm_bf16<<<dim3(INDIM/128, BATCH/64), 256, 0, stream>>>(
        h, w2_1t, b2_1, feat, feat, BATCH, INDIM, 1024, 1);
    gemm_bf16<<<dim3(512/128, BATCH/64), 256, 0, stream>>>(
        feat, w1_2t, b1_2, nullptr, h, BATCH, 512, INDIM, 1);
    gemm_bf16<<<dim3(INDIM/128, BATCH/64), 256, 0, stream>>>(
        h, w2_2t, b2_2, feat, feat, BATCH, INDIM, 512, 1);

    // 3) head
    final_head<<<BATCH / 4, 256, 0, stream>>>(feat, linw, linb, out);
}